// Round 22
// baseline (102.869 us; speedup 1.0000x reference)
//
#include <hip/hip_runtime.h>
#include <hip/hip_bf16.h>
#include <hip/hip_cooperative_groups.h>

// Problem constants (from reference)
#define NB 4       // batch
#define CIN 32
#define TT 8       // time steps
#define NN 2000    // nodes
#define NE 16000   // edges
#define H1C 128
#define H2C 256
#define COUT 64
#define BT (NB*TT) // 32 graph replicas
#define BNN 2048   // padded node count
#define WINV (1.0f/65535.0f)

// =============== single cooperative kernel: S^3*X ; grid.sync ; epilogue ===============
// grid (8, 32) = 256 blocks (1/CU, co-resident), 1024 threads.
// Phase 1 (== round-18 k_sss, proven 44.6us): per-block LDS CSR build, 3 LDS
// propagation passes, C3 store. bt==1 blocks fold weights; block (0,0) emits r1/r2.
// grid.sync()
// Phase 2 (== k_out): each block computes 4 n-tiles of its bt:
// P = C3@W123 + r2*d1 + r1*d2 + b3; out = relu(P) transposed to [B][COUT][T][N].
__global__ __launch_bounds__(1024) void k_fused(
    const float* __restrict__ x,
    const int* __restrict__ src, const int* __restrict__ dst,
    const float* __restrict__ ew,
    const float* __restrict__ W1, const float* __restrict__ b1,
    const float* __restrict__ W2, const float* __restrict__ b2,
    const float* __restrict__ W3, const float* __restrict__ b3,
    float* __restrict__ r1f, float* __restrict__ r2f,
    float* __restrict__ W123_g, float* __restrict__ d1_g, float* __restrict__ d2_g,
    float* __restrict__ C3,     // [bt][32][2000] channel-major
    float* __restrict__ out)    // [B][COUT][T][N]
{
    __shared__ unsigned int cmp[NE];     // 64000 B packed edges (src<<16 | w16), CSR order
    __shared__ float4 Y[BNN];            // 32768 B node feature vectors (4 ch)
    __shared__ float  idg[BNN];          // 8192 B 1/deg
    __shared__ unsigned int rp[BNN + 1]; // 8196 B rowptr
    __shared__ int cc_[BNN];             // 8192 B count, then cur
    __shared__ int ssc[256];             // 1024 B scan temp

    const int tid = threadIdx.x;
    const int cg = blockIdx.x, bt = blockIdx.y;
    const int b = bt >> 3, t = bt & 7;

    // ---- weight folding (blocks bt==1 only), cmp region as scratch ----
    if (bt == 1) {
        float* W3s  = (float*)cmp;            // 2048 floats
        float* W23s = (float*)cmp + H2C * 8;  // 1032 floats (rows 0..127 = W2@W3, 128 = b2@W3)
        const int j0 = cg * 8;

        for (int i = tid; i < H2C * 8; i += 1024)
            W3s[i] = W3[(size_t)(i >> 3) * COUT + j0 + (i & 7)];
        __syncthreads();

        for (int r = tid >> 3; r < H1C + 1; r += 128) {
            int j = tid & 7;
            const float* wrow = (r < H1C) ? (W2 + (size_t)r * H2C) : b2;
            float a0 = 0, a1 = 0, a2 = 0, a3 = 0;
            for (int k = 0; k < H2C; k += 4) {
                float4 wv = *(const float4*)(wrow + k);
                a0 += wv.x * W3s[(k + 0) * 8 + j];
                a1 += wv.y * W3s[(k + 1) * 8 + j];
                a2 += wv.z * W3s[(k + 2) * 8 + j];
                a3 += wv.w * W3s[(k + 3) * 8 + j];
            }
            W23s[r * 8 + j] = (a0 + a1) + (a2 + a3);
        }
        __syncthreads();

        for (int r = tid >> 3; r < CIN + 1; r += 128) {
            int j = tid & 7;
            const float* wrow = (r < CIN) ? (W1 + (size_t)r * H1C) : b1;
            float a0 = 0, a1 = 0, a2 = 0, a3 = 0;
            for (int k = 0; k < H1C; k += 4) {
                float4 wv = *(const float4*)(wrow + k);
                a0 += wv.x * W23s[(k + 0) * 8 + j];
                a1 += wv.y * W23s[(k + 1) * 8 + j];
                a2 += wv.z * W23s[(k + 2) * 8 + j];
                a3 += wv.w * W23s[(k + 3) * 8 + j];
            }
            float acc = (a0 + a1) + (a2 + a3);
            if (r < CIN) W123_g[(size_t)r * COUT + j0 + j] = acc;
            else         d1_g[j0 + j] = acc;
        }
        if (tid < 8) d2_g[j0 + tid] = W23s[H1C * 8 + tid];
        __syncthreads();   // cmp scratch free again
    }

    // ---- build exact CSR in LDS: count -> scan -> fill ----
    for (int i = tid; i < BNN; i += 1024) cc_[i] = 0;
    __syncthreads();
    #pragma unroll
    for (int i = 0; i < 16; i++) {
        int e = tid + i * 1024;
        if (e < NE) atomicAdd(&cc_[dst[e]], 1);    // native ds_add
    }
    __syncthreads();

    int local[8];
    if (tid < 256) {
        int base = tid * 8, sum = 0;
        #pragma unroll
        for (int i = 0; i < 8; i++) {
            int v = cc_[base + i];
            local[i] = sum;
            sum += v;
        }
        ssc[tid] = sum;
    }
    __syncthreads();
    for (int off = 1; off < 256; off <<= 1) {
        int v = 0;
        if (tid < 256 && tid >= off) v = ssc[tid - off];
        __syncthreads();
        if (tid < 256 && tid >= off) ssc[tid] += v;
        __syncthreads();
    }
    if (tid < 256) {
        int ce = (tid > 0) ? ssc[tid - 1] : 0;
        int base = tid * 8;
        #pragma unroll
        for (int i = 0; i < 8; i++) {
            int v = ce + local[i];
            rp[base + i] = v;
            cc_[base + i] = v;      // cur
        }
        if (tid == 255) rp[BNN] = ssc[255];
    }
    __syncthreads();

    #pragma unroll
    for (int i = 0; i < 16; i++) {
        int e = tid + i * 1024;
        if (e < NE) {
            int d = dst[e];
            unsigned int w16 = __float2uint_rn(ew[e] * 65535.0f);
            if (w16 > 65535u) w16 = 65535u;
            int pos = atomicAdd(&cc_[d], 1);       // native ds_add_rtn
            cmp[pos] = ((unsigned int)src[e] << 16) | w16;
        }
    }
    __syncthreads();

    // ---- deg -> idg ----
    for (int n = tid; n < BNN; n += 1024) {
        float s = 0.f;
        for (unsigned int p = rp[n]; p < rp[n + 1]; p++)
            s += (float)(cmp[p] & 0xffffu);
        idg[n] = 1.0f / (1.0f + s * WINV);
    }
    __syncthreads();

    // ---- block (0,0): r1 = S*1, r2 = S*r1 (Y as scalar scratch) ----
    if (cg == 0 && bt == 0) {
        float* Ys = (float*)Y;   // [0..2047]=dinv, [2048..4095]=u
        for (int n = tid; n < BNN; n += 1024) Ys[n] = sqrtf(idg[n]);
        __syncthreads();
        for (int n = tid; n < NN; n += 1024) {
            float s = 0.f;
            for (unsigned int p = rp[n]; p < rp[n + 1]; p++) {
                unsigned int g = cmp[p];
                s += (float)(g & 0xffffu) * Ys[g >> 16];
            }
            float r = Ys[n] * (Ys[n] + s * WINV);
            r1f[n] = r;
            Ys[BNN + n] = Ys[n] * r;
        }
        __syncthreads();
        for (int n = tid; n < NN; n += 1024) {
            float s = 0.f;
            for (unsigned int p = rp[n]; p < rp[n + 1]; p++) {
                unsigned int g = cmp[p];
                s += (float)(g & 0xffffu) * Ys[BNN + (g >> 16)];
            }
            r2f[n] = Ys[n] * (Ys[BNN + n] + s * WINV);
        }
        __syncthreads();
    }

    // ---- stage W0 = x * sqrt(idg)  (= D^-1 D^{1/2} x) ----
    for (int n = tid; n < NN; n += 1024) {
        float sq = sqrtf(idg[n]);
        float4 v;
        v.x = x[(((size_t)b * CIN + cg * 4 + 0) * TT + t) * NN + n] * sq;
        v.y = x[(((size_t)b * CIN + cg * 4 + 1) * TT + t) * NN + n] * sq;
        v.z = x[(((size_t)b * CIN + cg * 4 + 2) * TT + t) * NN + n] * sq;
        v.w = x[(((size_t)b * CIN + cg * 4 + 3) * TT + t) * NN + n] * sq;
        Y[n] = v;
    }
    __syncthreads();

    // ---- three propagation passes, all LDS; dual-node fused loop ----
    const int n0 = tid, n1 = tid + 1024;
    const unsigned int rp0 = rp[n0], re0 = rp[n0 + 1];
    const unsigned int rp1 = rp[n1], re1 = rp[n1 + 1];
    const int cn0 = (int)(re0 - rp0), cn1 = (int)(re1 - rp1);
    const int mx = max(cn0, cn1);

    for (int pass = 0; pass < 3; pass++) {
        float4 a0 = Y[n0];
        float4 a1 = Y[n1];
        float sx0 = 0, sy0 = 0, sz0 = 0, sw0 = 0;
        float sx1 = 0, sy1 = 0, sz1 = 0, sw1 = 0;
        for (int k = 0; k < mx; k++) {
            if (k < cn0) {
                unsigned int g = cmp[rp0 + k];
                float w = (float)(g & 0xffffu);
                float4 y = Y[g >> 16];
                sx0 += w * y.x; sy0 += w * y.y; sz0 += w * y.z; sw0 += w * y.w;
            }
            if (k < cn1) {
                unsigned int g = cmp[rp1 + k];
                float w = (float)(g & 0xffffu);
                float4 y = Y[g >> 16];
                sx1 += w * y.x; sy1 += w * y.y; sz1 += w * y.z; sw1 += w * y.w;
            }
        }
        a0.x += sx0 * WINV; a0.y += sy0 * WINV; a0.z += sz0 * WINV; a0.w += sw0 * WINV;
        a1.x += sx1 * WINV; a1.y += sy1 * WINV; a1.z += sz1 * WINV; a1.w += sw1 * WINV;

        if (pass < 2) {
            __syncthreads();   // all reads of Y done
            float g0 = idg[n0];
            Y[n0] = make_float4(a0.x * g0, a0.y * g0, a0.z * g0, a0.w * g0);
            float g1 = idg[n1];
            Y[n1] = make_float4(a1.x * g1, a1.y * g1, a1.z * g1, a1.w * g1);
            __syncthreads();
        } else {
            // final: C3 = a * sqrt(idg), straight to global (coalesced per channel)
            float s0 = sqrtf(idg[n0]);
            float* base = C3 + ((size_t)bt * CIN + cg * 4) * NN;
            base[0 * NN + n0] = a0.x * s0;
            base[1 * NN + n0] = a0.y * s0;
            base[2 * NN + n0] = a0.z * s0;
            base[3 * NN + n0] = a0.w * s0;
            if (n1 < NN) {
                float s1 = sqrtf(idg[n1]);
                base[0 * NN + n1] = a1.x * s1;
                base[1 * NN + n1] = a1.y * s1;
                base[2 * NN + n1] = a1.z * s1;
                base[3 * NN + n1] = a1.w * s1;
            }
        }
    }

    // ================= grid-wide sync: all C3 / W123 / d1 / d2 / r1 / r2 visible =================
    cooperative_groups::this_grid().sync();

    // ================= phase 2: epilogue (4 n-tiles per block) =================
    // LDS aliases inside cmp (64000 B >= 34.3 KB used)
    float* Wsl = (float*)cmp;          // 2048: W123 [k][c] row-major (k*64 + c)
    float* Csl = (float*)cmp + 2048;   // 2048: C3 slice [ch][nn] (ch*64 + nn)
    float* Osl = (float*)cmp + 4096;   // 64*65 = 4160
    float* d1s = (float*)cmp + 8256;   // 64
    float* d2s = d1s + 64;             // 64
    float* b3s = d2s + 64;             // 64
    float* r1s = b3s + 64;             // 64
    float* r2s = r1s + 64;             // 64

    for (int i = tid; i < 2048; i += 1024) Wsl[i] = W123_g[i];
    if (tid < 64) {
        d1s[tid] = d1_g[tid];
        d2s[tid] = d2_g[tid];
        b3s[tid] = b3[tid];
    }
    __syncthreads();

    const int c = tid & 63, g = tid >> 6;   // g: 0..15, wave-uniform
    #pragma unroll
    for (int q = 0; q < 4; q++) {
        const int nt0 = (cg * 4 + q) * 64;
        for (int i = tid; i < CIN * 64; i += 1024) {
            int ch = i >> 6, nn = i & 63;
            int n = nt0 + nn;
            Csl[ch * 64 + nn] = (n < NN) ? C3[((size_t)bt * CIN + ch) * NN + n] : 0.f;
        }
        if (tid < 64) {
            int n = nt0 + tid;
            r1s[tid] = (n < NN) ? r1f[n] : 0.f;
            r2s[tid] = (n < NN) ? r2f[n] : 0.f;
        }
        __syncthreads();

        #pragma unroll
        for (int i = 0; i < 4; i++) {
            int nn = g * 4 + i;   // wave-uniform -> Csl reads broadcast
            float acc = r2s[nn] * d1s[c] + r1s[nn] * d2s[c] + b3s[c];
            #pragma unroll
            for (int k = 0; k < CIN; k++)
                acc += Csl[k * 64 + nn] * Wsl[k * 64 + c];
            Osl[nn * 65 + c] = fmaxf(acc, 0.f);
        }
        __syncthreads();

        // transposed store: out[((b*COUT + cc)*TT + t)*NN + n], coalesced over n
        #pragma unroll
        for (int pass = 0; pass < 4; pass++) {
            int cc = g + pass * 16;
            int n = nt0 + c;
            if (n < NN)
                out[(((size_t)b * COUT + cc) * TT + t) * NN + n] = Osl[c * 65 + cc];
        }
        __syncthreads();   // before next tile overwrites Csl/Osl
    }
}

// ---------------- launch: ONE cooperative dispatch ----------------

extern "C" void kernel_launch(void* const* d_in, const int* in_sizes, int n_in,
                              void* d_out, int out_size, void* d_ws, size_t ws_size,
                              hipStream_t stream) {
    (void)in_sizes; (void)n_in; (void)out_size; (void)ws_size;

    const float* x  = (const float*)d_in[0];
    const int*   ei = (const int*)d_in[1];
    const float* ew = (const float*)d_in[2];
    const float* W1 = (const float*)d_in[3];
    const float* b1 = (const float*)d_in[4];
    const float* W2 = (const float*)d_in[5];
    const float* b2 = (const float*)d_in[6];
    const float* W3 = (const float*)d_in[7];
    const float* b3 = (const float*)d_in[8];
    float* out = (float*)d_out;

    const int* src = ei;
    const int* dst = ei + NE;

    // workspace layout (float units) — all pure overwrites, replay-safe
    float* wsf  = (float*)d_ws;
    float* r1f  = wsf;            // 2048
    float* r2f  = wsf + 2048;     // 2048
    float* W123 = wsf + 4096;     // 2048
    float* d1   = wsf + 6144;     // 64
    float* d2   = wsf + 6208;     // 64
    float* C3   = wsf + 6272;     // 32*32*2000 floats

    void* args[] = {
        (void*)&x, (void*)&src, (void*)&dst, (void*)&ew,
        (void*)&W1, (void*)&b1, (void*)&W2, (void*)&b2, (void*)&W3, (void*)&b3,
        (void*)&r1f, (void*)&r2f, (void*)&W123, (void*)&d1, (void*)&d2,
        (void*)&C3, (void*)&out
    };
    hipLaunchCooperativeKernel((void*)k_fused, dim3(8, BT), dim3(1024),
                               args, 0, stream);
}

// Round 23
// 64.102 us; speedup vs baseline: 1.6048x; 1.6048x over previous
//
#include <hip/hip_runtime.h>
#include <hip/hip_bf16.h>

// Problem constants (from reference)
#define NB 4       // batch
#define CIN 32
#define TT 8       // time steps
#define NN 2000    // nodes
#define NE 16000   // edges
#define H1C 128
#define H2C 256
#define COUT 64
#define BT (NB*TT) // 32 graph replicas
#define BNN 2048   // padded node count
#define WINV (1.0f/65535.0f)

// =============== kernel 1: fully self-contained S^3*X (round-18 body + degree sort) ===============
// grid (8, 32) = 256 blocks (1/CU), 1024 threads.
// Per block: exact CSR in LDS (count -> scan -> fill, native int LDS atomics),
// deg, counting-sort nodes by exact row length (divergence fix ONLY — float4 Y
// and natural CSR kept from round 18), 3 LDS propagation passes on sorted node
// pairs, coalesced store sweep.
// bt==1 blocks also fold weights; block (0,0) also emits r1/r2.
__global__ __launch_bounds__(1024) void k_sss(
    const float* __restrict__ x,
    const int* __restrict__ src, const int* __restrict__ dst,
    const float* __restrict__ ew,
    const float* __restrict__ W1, const float* __restrict__ b1,
    const float* __restrict__ W2, const float* __restrict__ b2,
    const float* __restrict__ W3,
    float* __restrict__ r1f, float* __restrict__ r2f,
    float* __restrict__ W123_g, float* __restrict__ d1_g, float* __restrict__ d2_g,
    float* __restrict__ C3)     // [bt][32][2000] channel-major
{
    __shared__ unsigned int cmp[NE];     // 64000 B packed edges (src<<16 | w16), CSR order
    __shared__ float4 Y[BNN];            // 32768 B node feature vectors (4 ch)
    __shared__ float  idg[BNN];          // 8192 B 1/deg
    __shared__ unsigned int rp[BNN + 1]; // 8196 B rowptr
    __shared__ int cc_[BNN];             // 8192 B count/cursor, then ord[]
    __shared__ int ssc[256];             // 1024 B scan temp + sort hist/cursors

    const int tid = threadIdx.x;
    const int cg = blockIdx.x, bt = blockIdx.y;
    const int b = bt >> 3, t = bt & 7;

    // ---- weight folding (blocks bt==1 only), cmp region as scratch ----
    if (bt == 1) {
        float* W3s  = (float*)cmp;            // 2048 floats
        float* W23s = (float*)cmp + H2C * 8;  // 1032 floats (rows 0..127 = W2@W3, 128 = b2@W3)
        const int j0 = cg * 8;

        for (int i = tid; i < H2C * 8; i += 1024)
            W3s[i] = W3[(size_t)(i >> 3) * COUT + j0 + (i & 7)];
        __syncthreads();

        for (int r = tid >> 3; r < H1C + 1; r += 128) {
            int j = tid & 7;
            const float* wrow = (r < H1C) ? (W2 + (size_t)r * H2C) : b2;
            float a0 = 0, a1 = 0, a2 = 0, a3 = 0;
            for (int k = 0; k < H2C; k += 4) {
                float4 wv = *(const float4*)(wrow + k);
                a0 += wv.x * W3s[(k + 0) * 8 + j];
                a1 += wv.y * W3s[(k + 1) * 8 + j];
                a2 += wv.z * W3s[(k + 2) * 8 + j];
                a3 += wv.w * W3s[(k + 3) * 8 + j];
            }
            W23s[r * 8 + j] = (a0 + a1) + (a2 + a3);
        }
        __syncthreads();

        for (int r = tid >> 3; r < CIN + 1; r += 128) {
            int j = tid & 7;
            const float* wrow = (r < CIN) ? (W1 + (size_t)r * H1C) : b1;
            float a0 = 0, a1 = 0, a2 = 0, a3 = 0;
            for (int k = 0; k < H1C; k += 4) {
                float4 wv = *(const float4*)(wrow + k);
                a0 += wv.x * W23s[(k + 0) * 8 + j];
                a1 += wv.y * W23s[(k + 1) * 8 + j];
                a2 += wv.z * W23s[(k + 2) * 8 + j];
                a3 += wv.w * W23s[(k + 3) * 8 + j];
            }
            float acc = (a0 + a1) + (a2 + a3);
            if (r < CIN) W123_g[(size_t)r * COUT + j0 + j] = acc;
            else         d1_g[j0 + j] = acc;
        }
        if (tid < 8) d2_g[j0 + tid] = W23s[H1C * 8 + tid];
        __syncthreads();   // cmp scratch free again
    }

    // ---- build exact CSR in LDS: count -> scan -> fill ----
    for (int i = tid; i < BNN; i += 1024) cc_[i] = 0;
    __syncthreads();
    #pragma unroll
    for (int i = 0; i < 16; i++) {
        int e = tid + i * 1024;
        if (e < NE) atomicAdd(&cc_[dst[e]], 1);    // native ds_add
    }
    __syncthreads();

    int local[8];
    if (tid < 256) {
        int base = tid * 8, sum = 0;
        #pragma unroll
        for (int i = 0; i < 8; i++) {
            int v = cc_[base + i];
            local[i] = sum;
            sum += v;
        }
        ssc[tid] = sum;
    }
    __syncthreads();
    for (int off = 1; off < 256; off <<= 1) {
        int v = 0;
        if (tid < 256 && tid >= off) v = ssc[tid - off];
        __syncthreads();
        if (tid < 256 && tid >= off) ssc[tid] += v;
        __syncthreads();
    }
    if (tid < 256) {
        int ce = (tid > 0) ? ssc[tid - 1] : 0;
        int base = tid * 8;
        #pragma unroll
        for (int i = 0; i < 8; i++) {
            int v = ce + local[i];
            rp[base + i] = v;
            cc_[base + i] = v;      // cur
        }
        if (tid == 255) rp[BNN] = ssc[255];
    }
    __syncthreads();

    #pragma unroll
    for (int i = 0; i < 16; i++) {
        int e = tid + i * 1024;
        if (e < NE) {
            int d = dst[e];
            unsigned int w16 = __float2uint_rn(ew[e] * 65535.0f);
            if (w16 > 65535u) w16 = 65535u;
            int pos = atomicAdd(&cc_[d], 1);       // native ds_add_rtn
            cmp[pos] = ((unsigned int)src[e] << 16) | w16;
        }
    }
    __syncthreads();

    // ---- deg -> idg ----
    for (int n = tid; n < BNN; n += 1024) {
        float s = 0.f;
        for (unsigned int p = rp[n]; p < rp[n + 1]; p++)
            s += (float)(cmp[p] & 0xffffu);
        idg[n] = 1.0f / (1.0f + s * WINV);
    }
    __syncthreads();

    // ---- counting sort by exact row length -> ord in cc_ (cursor role done) ----
    if (tid < 128) ssc[tid] = 0;   // 64 hist + 64 cursors
    __syncthreads();
    #pragma unroll
    for (int h = 0; h < 2; h++) {
        int n = tid + h * 1024;
        int bin = min((int)(rp[n + 1] - rp[n]), 63);
        atomicAdd(&ssc[bin], 1);
    }
    __syncthreads();
    if (tid < 64) {
        int v = ssc[tid], s = v;
        #pragma unroll
        for (int off = 1; off < 64; off <<= 1) {
            int u = __shfl_up(s, off);
            if (tid >= off) s += u;
        }
        ssc[64 + tid] = s - v;   // exclusive prefix
    }
    __syncthreads();
    #pragma unroll
    for (int h = 0; h < 2; h++) {
        int n = tid + h * 1024;
        int bin = min((int)(rp[n + 1] - rp[n]), 63);
        int pos = atomicAdd(&ssc[64 + bin], 1);
        cc_[pos] = n;            // ord: permutation of [0, BNN)
    }
    __syncthreads();

    // ---- block (0,0): r1 = S*1, r2 = S*r1 (Y as scalar scratch) ----
    if (cg == 0 && bt == 0) {
        float* Ys = (float*)Y;   // [0..2047]=dinv, [2048..4095]=u
        for (int n = tid; n < BNN; n += 1024) Ys[n] = sqrtf(idg[n]);
        __syncthreads();
        for (int n = tid; n < NN; n += 1024) {
            float s = 0.f;
            for (unsigned int p = rp[n]; p < rp[n + 1]; p++) {
                unsigned int g = cmp[p];
                s += (float)(g & 0xffffu) * Ys[g >> 16];
            }
            float r = Ys[n] * (Ys[n] + s * WINV);
            r1f[n] = r;
            Ys[BNN + n] = Ys[n] * r;
        }
        __syncthreads();
        for (int n = tid; n < NN; n += 1024) {
            float s = 0.f;
            for (unsigned int p = rp[n]; p < rp[n + 1]; p++) {
                unsigned int g = cmp[p];
                s += (float)(g & 0xffffu) * Ys[BNN + (g >> 16)];
            }
            r2f[n] = Ys[n] * (Ys[BNN + n] + s * WINV);
        }
        __syncthreads();
    }

    // ---- stage W0 = x * sqrt(idg)  (= D^-1 D^{1/2} x); zero the tail ----
    for (int n = tid; n < BNN; n += 1024) {
        if (n < NN) {
            float sq = sqrtf(idg[n]);
            float4 v;
            v.x = x[(((size_t)b * CIN + cg * 4 + 0) * TT + t) * NN + n] * sq;
            v.y = x[(((size_t)b * CIN + cg * 4 + 1) * TT + t) * NN + n] * sq;
            v.z = x[(((size_t)b * CIN + cg * 4 + 2) * TT + t) * NN + n] * sq;
            v.w = x[(((size_t)b * CIN + cg * 4 + 3) * TT + t) * NN + n] * sq;
            Y[n] = v;
        } else {
            Y[n] = make_float4(0.f, 0.f, 0.f, 0.f);
        }
    }
    __syncthreads();

    // ---- three propagation passes on SORTED node pairs (round-18 float4 body) ----
    const int na = cc_[2 * tid], nb = cc_[2 * tid + 1];
    const unsigned int rp0 = rp[na], re0 = rp[na + 1];
    const unsigned int rp1 = rp[nb], re1 = rp[nb + 1];
    const int cn0 = (int)(re0 - rp0), cn1 = (int)(re1 - rp1);
    const int mx = max(cn0, cn1);   // sorted-adjacent -> near-equal across the wave

    for (int pass = 0; pass < 3; pass++) {
        float4 a0 = Y[na];
        float4 a1 = Y[nb];
        float sx0 = 0, sy0 = 0, sz0 = 0, sw0 = 0;
        float sx1 = 0, sy1 = 0, sz1 = 0, sw1 = 0;
        for (int k = 0; k < mx; k++) {
            if (k < cn0) {
                unsigned int g = cmp[rp0 + k];
                float w = (float)(g & 0xffffu);
                float4 y = Y[g >> 16];
                sx0 += w * y.x; sy0 += w * y.y; sz0 += w * y.z; sw0 += w * y.w;
            }
            if (k < cn1) {
                unsigned int g = cmp[rp1 + k];
                float w = (float)(g & 0xffffu);
                float4 y = Y[g >> 16];
                sx1 += w * y.x; sy1 += w * y.y; sz1 += w * y.z; sw1 += w * y.w;
            }
        }
        a0.x += sx0 * WINV; a0.y += sy0 * WINV; a0.z += sz0 * WINV; a0.w += sw0 * WINV;
        a1.x += sx1 * WINV; a1.y += sy1 * WINV; a1.z += sz1 * WINV; a1.w += sw1 * WINV;

        __syncthreads();   // all reads of Y done
        float sa = (pass < 2) ? idg[na] : sqrtf(idg[na]);
        float sb = (pass < 2) ? idg[nb] : sqrtf(idg[nb]);
        Y[na] = make_float4(a0.x * sa, a0.y * sa, a0.z * sa, a0.w * sa);
        Y[nb] = make_float4(a1.x * sb, a1.y * sb, a1.z * sb, a1.w * sb);
        __syncthreads();
    }

    // ---- coalesced store sweep ----
    float* base = C3 + ((size_t)bt * CIN + cg * 4) * NN;
    for (int n = tid; n < NN; n += 1024) {
        float4 v = Y[n];
        base[0 * NN + n] = v.x;
        base[1 * NN + n] = v.y;
        base[2 * NN + n] = v.z;
        base[3 * NN + n] = v.w;
    }
}

// =============== kernel 2: P = C3@W123 + r2*d1 + r1*d2 + b3; out = relu(P), transposed ===============
__global__ __launch_bounds__(256) void k_out(
    const float* __restrict__ C3,       // [bt][32][2000]
    const float* __restrict__ W123,     // 32x64
    const float* __restrict__ d1, const float* __restrict__ d2,
    const float* __restrict__ b3,
    const float* __restrict__ r1f, const float* __restrict__ r2f,
    float* __restrict__ out)            // [B][COUT][T][N]
{
    __shared__ float Cs[CIN][65];
    __shared__ float Ws[CIN][64];
    __shared__ float Os[64][65];
    __shared__ float d1s[64], d2s[64], b3s[64], r1s[64], r2s[64];
    const int tid = threadIdx.x;
    const int bt = blockIdx.y, b = bt >> 3, t = bt & 7;
    const int n0 = blockIdx.x * 64;

    for (int i = tid; i < CIN * 64; i += 256) {
        int ch = i >> 6, nn = i & 63;
        int n = n0 + nn;
        Cs[ch][nn] = (n < NN) ? C3[((size_t)bt * CIN + ch) * NN + n] : 0.f;
    }
    for (int i = tid; i < CIN * 64; i += 256)
        Ws[i >> 6][i & 63] = W123[i];
    if (tid < 64) {
        d1s[tid] = d1[tid];
        d2s[tid] = d2[tid];
        b3s[tid] = b3[tid];
        int n = n0 + tid;
        r1s[tid] = (n < NN) ? r1f[n] : 0.f;
        r2s[tid] = (n < NN) ? r2f[n] : 0.f;
    }
    __syncthreads();

    const int c = tid & 63, g = tid >> 6;
    for (int i = 0; i < 16; i++) {
        int nn = g * 16 + i;
        float acc = r2s[nn] * d1s[c] + r1s[nn] * d2s[c] + b3s[c];
        #pragma unroll
        for (int k = 0; k < CIN; k++) acc += Cs[k][nn] * Ws[k][c];
        Os[nn][c] = fmaxf(acc, 0.f);
    }
    __syncthreads();

    #pragma unroll
    for (int pass = 0; pass < 16; pass++) {
        int cc = g + pass * 4;
        int n = n0 + (tid & 63);
        if (n < NN)
            out[(((size_t)b * COUT + cc) * TT + t) * NN + n] = Os[tid & 63][cc];
    }
}

// ---------------- launch: exactly TWO dispatches ----------------

extern "C" void kernel_launch(void* const* d_in, const int* in_sizes, int n_in,
                              void* d_out, int out_size, void* d_ws, size_t ws_size,
                              hipStream_t stream) {
    (void)in_sizes; (void)n_in; (void)out_size; (void)ws_size;

    const float* x  = (const float*)d_in[0];
    const int*   ei = (const int*)d_in[1];
    const float* ew = (const float*)d_in[2];
    const float* W1 = (const float*)d_in[3];
    const float* b1 = (const float*)d_in[4];
    const float* W2 = (const float*)d_in[5];
    const float* b2 = (const float*)d_in[6];
    const float* W3 = (const float*)d_in[7];
    const float* b3 = (const float*)d_in[8];
    float* out = (float*)d_out;

    const int* src = ei;
    const int* dst = ei + NE;

    // workspace layout (float units) — all pure overwrites, replay-safe
    float* wsf  = (float*)d_ws;
    float* r1f  = wsf;            // 2048
    float* r2f  = wsf + 2048;     // 2048
    float* W123 = wsf + 4096;     // 2048
    float* d1   = wsf + 6144;     // 64
    float* d2   = wsf + 6208;     // 64
    float* C3   = wsf + 6272;     // 32*32*2000 floats

    k_sss<<<dim3(8, BT), dim3(1024), 0, stream>>>(
        x, src, dst, ew, W1, b1, W2, b2, W3,
        r1f, r2f, W123, d1, d2, C3);

    k_out<<<dim3(32, BT), dim3(256), 0, stream>>>(
        C3, W123, d1, d2, b3, r1f, r2f, out);
}

// Round 24
// 58.101 us; speedup vs baseline: 1.7705x; 1.1033x over previous
//
#include <hip/hip_runtime.h>
#include <hip/hip_bf16.h>

// Problem constants (from reference)
#define NB 4       // batch
#define CIN 32
#define TT 8       // time steps
#define NN 2000    // nodes
#define NE 16000   // edges
#define H1C 128
#define H2C 256
#define COUT 64
#define BT (NB*TT) // 32 graph replicas
#define BNN 2048   // padded node count
#define WINV (1.0f/65535.0f)

// =============== kernel 1: fully self-contained S^3*X (round-18 body + 4-wide ILP) ===============
// grid (8, 32) = 256 blocks (1/CU), 1024 threads.
// Identical to the proven round-18 structure except the propagation edge loop is
// manually quad-unrolled: 4 consecutive cmp words loaded, tail masked by select,
// 4 INDEPENDENT Y reads in flight per node (x2 nodes = 8) to cover LDS latency.
__global__ __launch_bounds__(1024) void k_sss(
    const float* __restrict__ x,
    const int* __restrict__ src, const int* __restrict__ dst,
    const float* __restrict__ ew,
    const float* __restrict__ W1, const float* __restrict__ b1,
    const float* __restrict__ W2, const float* __restrict__ b2,
    const float* __restrict__ W3,
    float* __restrict__ r1f, float* __restrict__ r2f,
    float* __restrict__ W123_g, float* __restrict__ d1_g, float* __restrict__ d2_g,
    float* __restrict__ C3)     // [bt][32][2000] channel-major
{
    __shared__ unsigned int cmp[NE + 64]; // 64256 B packed edges + zeroed pad
    __shared__ float4 Y[BNN];            // 32768 B node feature vectors (4 ch)
    __shared__ float  idg[BNN];          // 8192 B 1/deg
    __shared__ unsigned int rp[BNN + 1]; // 8196 B rowptr
    __shared__ int cc_[BNN];             // 8192 B count, then cur
    __shared__ int ssc[256];             // 1024 B scan temp

    const int tid = threadIdx.x;
    const int cg = blockIdx.x, bt = blockIdx.y;
    const int b = bt >> 3, t = bt & 7;

    // ---- weight folding (blocks bt==1 only), cmp region as scratch ----
    if (bt == 1) {
        float* W3s  = (float*)cmp;            // 2048 floats
        float* W23s = (float*)cmp + H2C * 8;  // 1032 floats (rows 0..127 = W2@W3, 128 = b2@W3)
        const int j0 = cg * 8;

        for (int i = tid; i < H2C * 8; i += 1024)
            W3s[i] = W3[(size_t)(i >> 3) * COUT + j0 + (i & 7)];
        __syncthreads();

        for (int r = tid >> 3; r < H1C + 1; r += 128) {
            int j = tid & 7;
            const float* wrow = (r < H1C) ? (W2 + (size_t)r * H2C) : b2;
            float a0 = 0, a1 = 0, a2 = 0, a3 = 0;
            for (int k = 0; k < H2C; k += 4) {
                float4 wv = *(const float4*)(wrow + k);
                a0 += wv.x * W3s[(k + 0) * 8 + j];
                a1 += wv.y * W3s[(k + 1) * 8 + j];
                a2 += wv.z * W3s[(k + 2) * 8 + j];
                a3 += wv.w * W3s[(k + 3) * 8 + j];
            }
            W23s[r * 8 + j] = (a0 + a1) + (a2 + a3);
        }
        __syncthreads();

        for (int r = tid >> 3; r < CIN + 1; r += 128) {
            int j = tid & 7;
            const float* wrow = (r < CIN) ? (W1 + (size_t)r * H1C) : b1;
            float a0 = 0, a1 = 0, a2 = 0, a3 = 0;
            for (int k = 0; k < H1C; k += 4) {
                float4 wv = *(const float4*)(wrow + k);
                a0 += wv.x * W23s[(k + 0) * 8 + j];
                a1 += wv.y * W23s[(k + 1) * 8 + j];
                a2 += wv.z * W23s[(k + 2) * 8 + j];
                a3 += wv.w * W23s[(k + 3) * 8 + j];
            }
            float acc = (a0 + a1) + (a2 + a3);
            if (r < CIN) W123_g[(size_t)r * COUT + j0 + j] = acc;
            else         d1_g[j0 + j] = acc;
        }
        if (tid < 8) d2_g[j0 + tid] = W23s[H1C * 8 + tid];
        __syncthreads();   // cmp scratch free again
    }

    // ---- build exact CSR in LDS: count -> scan -> fill ----
    for (int i = tid; i < BNN; i += 1024) cc_[i] = 0;
    if (tid < 64) cmp[NE + tid] = 0u;   // zero the overrun pad
    __syncthreads();
    #pragma unroll
    for (int i = 0; i < 16; i++) {
        int e = tid + i * 1024;
        if (e < NE) atomicAdd(&cc_[dst[e]], 1);    // native ds_add
    }
    __syncthreads();

    int local[8];
    if (tid < 256) {
        int base = tid * 8, sum = 0;
        #pragma unroll
        for (int i = 0; i < 8; i++) {
            int v = cc_[base + i];
            local[i] = sum;
            sum += v;
        }
        ssc[tid] = sum;
    }
    __syncthreads();
    for (int off = 1; off < 256; off <<= 1) {
        int v = 0;
        if (tid < 256 && tid >= off) v = ssc[tid - off];
        __syncthreads();
        if (tid < 256 && tid >= off) ssc[tid] += v;
        __syncthreads();
    }
    if (tid < 256) {
        int ce = (tid > 0) ? ssc[tid - 1] : 0;
        int base = tid * 8;
        #pragma unroll
        for (int i = 0; i < 8; i++) {
            int v = ce + local[i];
            rp[base + i] = v;
            cc_[base + i] = v;      // cur
        }
        if (tid == 255) rp[BNN] = ssc[255];
    }
    __syncthreads();

    #pragma unroll
    for (int i = 0; i < 16; i++) {
        int e = tid + i * 1024;
        if (e < NE) {
            int d = dst[e];
            unsigned int w16 = __float2uint_rn(ew[e] * 65535.0f);
            if (w16 > 65535u) w16 = 65535u;
            int pos = atomicAdd(&cc_[d], 1);       // native ds_add_rtn
            cmp[pos] = ((unsigned int)src[e] << 16) | w16;
        }
    }
    __syncthreads();

    // ---- deg -> idg ----
    for (int n = tid; n < BNN; n += 1024) {
        float s = 0.f;
        for (unsigned int p = rp[n]; p < rp[n + 1]; p++)
            s += (float)(cmp[p] & 0xffffu);
        idg[n] = 1.0f / (1.0f + s * WINV);
    }
    __syncthreads();

    // ---- block (0,0): r1 = S*1, r2 = S*r1 (Y as scalar scratch) ----
    if (cg == 0 && bt == 0) {
        float* Ys = (float*)Y;   // [0..2047]=dinv, [2048..4095]=u
        for (int n = tid; n < BNN; n += 1024) Ys[n] = sqrtf(idg[n]);
        __syncthreads();
        for (int n = tid; n < NN; n += 1024) {
            float s = 0.f;
            for (unsigned int p = rp[n]; p < rp[n + 1]; p++) {
                unsigned int g = cmp[p];
                s += (float)(g & 0xffffu) * Ys[g >> 16];
            }
            float r = Ys[n] * (Ys[n] + s * WINV);
            r1f[n] = r;
            Ys[BNN + n] = Ys[n] * r;
        }
        __syncthreads();
        for (int n = tid; n < NN; n += 1024) {
            float s = 0.f;
            for (unsigned int p = rp[n]; p < rp[n + 1]; p++) {
                unsigned int g = cmp[p];
                s += (float)(g & 0xffffu) * Ys[BNN + (g >> 16)];
            }
            r2f[n] = Ys[n] * (Ys[BNN + n] + s * WINV);
        }
        __syncthreads();
    }

    // ---- stage W0 = x * sqrt(idg)  (= D^-1 D^{1/2} x) ----
    for (int n = tid; n < NN; n += 1024) {
        float sq = sqrtf(idg[n]);
        float4 v;
        v.x = x[(((size_t)b * CIN + cg * 4 + 0) * TT + t) * NN + n] * sq;
        v.y = x[(((size_t)b * CIN + cg * 4 + 1) * TT + t) * NN + n] * sq;
        v.z = x[(((size_t)b * CIN + cg * 4 + 2) * TT + t) * NN + n] * sq;
        v.w = x[(((size_t)b * CIN + cg * 4 + 3) * TT + t) * NN + n] * sq;
        Y[n] = v;
    }
    __syncthreads();

    // ---- three propagation passes; quad-unrolled, 8 independent Y loads in flight ----
    const int n0 = tid, n1 = tid + 1024;
    const unsigned int rp0 = rp[n0], re0 = rp[n0 + 1];
    const unsigned int rp1 = rp[n1], re1 = rp[n1 + 1];
    const int cn0 = (int)(re0 - rp0), cn1 = (int)(re1 - rp1);
    const int mx = max(cn0, cn1);

    for (int pass = 0; pass < 3; pass++) {
        float4 a0 = Y[n0];
        float4 a1 = Y[n1];
        float sx0 = 0, sy0 = 0, sz0 = 0, sw0 = 0;
        float sx1 = 0, sy1 = 0, sz1 = 0, sw1 = 0;
        for (int k = 0; k < mx; k += 4) {
            // node n0: 4 edges (tail masked to weight 0; pad keeps loads in-bounds)
            unsigned int u00 = cmp[rp0 + k + 0]; if (k + 0 >= cn0) u00 = 0u;
            unsigned int u01 = cmp[rp0 + k + 1]; if (k + 1 >= cn0) u01 = 0u;
            unsigned int u02 = cmp[rp0 + k + 2]; if (k + 2 >= cn0) u02 = 0u;
            unsigned int u03 = cmp[rp0 + k + 3]; if (k + 3 >= cn0) u03 = 0u;
            // node n1: 4 edges
            unsigned int u10 = cmp[rp1 + k + 0]; if (k + 0 >= cn1) u10 = 0u;
            unsigned int u11 = cmp[rp1 + k + 1]; if (k + 1 >= cn1) u11 = 0u;
            unsigned int u12 = cmp[rp1 + k + 2]; if (k + 2 >= cn1) u12 = 0u;
            unsigned int u13 = cmp[rp1 + k + 3]; if (k + 3 >= cn1) u13 = 0u;

            // 8 independent Y reads
            float4 y00 = Y[u00 >> 16], y01 = Y[u01 >> 16];
            float4 y02 = Y[u02 >> 16], y03 = Y[u03 >> 16];
            float4 y10 = Y[u10 >> 16], y11 = Y[u11 >> 16];
            float4 y12 = Y[u12 >> 16], y13 = Y[u13 >> 16];

            float w00 = (float)(u00 & 0xffffu), w01 = (float)(u01 & 0xffffu);
            float w02 = (float)(u02 & 0xffffu), w03 = (float)(u03 & 0xffffu);
            float w10 = (float)(u10 & 0xffffu), w11 = (float)(u11 & 0xffffu);
            float w12 = (float)(u12 & 0xffffu), w13 = (float)(u13 & 0xffffu);

            sx0 += w00 * y00.x + w01 * y01.x + w02 * y02.x + w03 * y03.x;
            sy0 += w00 * y00.y + w01 * y01.y + w02 * y02.y + w03 * y03.y;
            sz0 += w00 * y00.z + w01 * y01.z + w02 * y02.z + w03 * y03.z;
            sw0 += w00 * y00.w + w01 * y01.w + w02 * y02.w + w03 * y03.w;
            sx1 += w10 * y10.x + w11 * y11.x + w12 * y12.x + w13 * y13.x;
            sy1 += w10 * y10.y + w11 * y11.y + w12 * y12.y + w13 * y13.y;
            sz1 += w10 * y10.z + w11 * y11.z + w12 * y12.z + w13 * y13.z;
            sw1 += w10 * y10.w + w11 * y11.w + w12 * y12.w + w13 * y13.w;
        }
        a0.x += sx0 * WINV; a0.y += sy0 * WINV; a0.z += sz0 * WINV; a0.w += sw0 * WINV;
        a1.x += sx1 * WINV; a1.y += sy1 * WINV; a1.z += sz1 * WINV; a1.w += sw1 * WINV;

        if (pass < 2) {
            __syncthreads();   // all reads of Y done
            float g0 = idg[n0];
            Y[n0] = make_float4(a0.x * g0, a0.y * g0, a0.z * g0, a0.w * g0);
            float g1 = idg[n1];
            Y[n1] = make_float4(a1.x * g1, a1.y * g1, a1.z * g1, a1.w * g1);
            __syncthreads();
        } else {
            // final: C3 = a * sqrt(idg), straight to global (coalesced per channel)
            float s0 = sqrtf(idg[n0]);
            float* base = C3 + ((size_t)bt * CIN + cg * 4) * NN;
            base[0 * NN + n0] = a0.x * s0;
            base[1 * NN + n0] = a0.y * s0;
            base[2 * NN + n0] = a0.z * s0;
            base[3 * NN + n0] = a0.w * s0;
            if (n1 < NN) {
                float s1 = sqrtf(idg[n1]);
                base[0 * NN + n1] = a1.x * s1;
                base[1 * NN + n1] = a1.y * s1;
                base[2 * NN + n1] = a1.z * s1;
                base[3 * NN + n1] = a1.w * s1;
            }
        }
    }
}

// =============== kernel 2: P = C3@W123 + r2*d1 + r1*d2 + b3; out = relu(P), transposed ===============
__global__ __launch_bounds__(256) void k_out(
    const float* __restrict__ C3,       // [bt][32][2000]
    const float* __restrict__ W123,     // 32x64
    const float* __restrict__ d1, const float* __restrict__ d2,
    const float* __restrict__ b3,
    const float* __restrict__ r1f, const float* __restrict__ r2f,
    float* __restrict__ out)            // [B][COUT][T][N]
{
    __shared__ float Cs[CIN][65];
    __shared__ float Ws[CIN][64];
    __shared__ float Os[64][65];
    __shared__ float d1s[64], d2s[64], b3s[64], r1s[64], r2s[64];
    const int tid = threadIdx.x;
    const int bt = blockIdx.y, b = bt >> 3, t = bt & 7;
    const int n0 = blockIdx.x * 64;

    for (int i = tid; i < CIN * 64; i += 256) {
        int ch = i >> 6, nn = i & 63;
        int n = n0 + nn;
        Cs[ch][nn] = (n < NN) ? C3[((size_t)bt * CIN + ch) * NN + n] : 0.f;
    }
    for (int i = tid; i < CIN * 64; i += 256)
        Ws[i >> 6][i & 63] = W123[i];
    if (tid < 64) {
        d1s[tid] = d1[tid];
        d2s[tid] = d2[tid];
        b3s[tid] = b3[tid];
        int n = n0 + tid;
        r1s[tid] = (n < NN) ? r1f[n] : 0.f;
        r2s[tid] = (n < NN) ? r2f[n] : 0.f;
    }
    __syncthreads();

    const int c = tid & 63, g = tid >> 6;
    for (int i = 0; i < 16; i++) {
        int nn = g * 16 + i;
        float acc = r2s[nn] * d1s[c] + r1s[nn] * d2s[c] + b3s[c];
        #pragma unroll
        for (int k = 0; k < CIN; k++) acc += Cs[k][nn] * Ws[k][c];
        Os[nn][c] = fmaxf(acc, 0.f);
    }
    __syncthreads();

    #pragma unroll
    for (int pass = 0; pass < 16; pass++) {
        int cc = g + pass * 4;
        int n = n0 + (tid & 63);
        if (n < NN)
            out[(((size_t)b * COUT + cc) * TT + t) * NN + n] = Os[tid & 63][cc];
    }
}

// ---------------- launch: exactly TWO dispatches ----------------

extern "C" void kernel_launch(void* const* d_in, const int* in_sizes, int n_in,
                              void* d_out, int out_size, void* d_ws, size_t ws_size,
                              hipStream_t stream) {
    (void)in_sizes; (void)n_in; (void)out_size; (void)ws_size;

    const float* x  = (const float*)d_in[0];
    const int*   ei = (const int*)d_in[1];
    const float* ew = (const float*)d_in[2];
    const float* W1 = (const float*)d_in[3];
    const float* b1 = (const float*)d_in[4];
    const float* W2 = (const float*)d_in[5];
    const float* b2 = (const float*)d_in[6];
    const float* W3 = (const float*)d_in[7];
    const float* b3 = (const float*)d_in[8];
    float* out = (float*)d_out;

    const int* src = ei;
    const int* dst = ei + NE;

    // workspace layout (float units) — all pure overwrites, replay-safe
    float* wsf  = (float*)d_ws;
    float* r1f  = wsf;            // 2048
    float* r2f  = wsf + 2048;     // 2048
    float* W123 = wsf + 4096;     // 2048
    float* d1   = wsf + 6144;     // 64
    float* d2   = wsf + 6208;     // 64
    float* C3   = wsf + 6272;     // 32*32*2000 floats

    k_sss<<<dim3(8, BT), dim3(1024), 0, stream>>>(
        x, src, dst, ew, W1, b1, W2, b2, W3,
        r1f, r2f, W123, d1, d2, C3);

    k_out<<<dim3(32, BT), dim3(256), 0, stream>>>(
        C3, W123, d1, d2, b3, r1f, r2f, out);
}